// Round 1
// baseline (387.105 us; speedup 1.0000x reference)
//
#include <hip/hip_runtime.h>
#include <hip/hip_bf16.h>

// SpatialAttention: out[b,i,j] = softmax_j( sum_c w3[c] * tanh(x1[b,i,c] + x2[b,j,c]) )
// where x1 = x@W1^T, x2 = x@W2^T.  B=4, N=1024, C=64.
//
// tanh(x) = 1 - 2/(e^{2x}+1).  Pre-scale projections by K2 = 2*log2(e) so
// t = exp2(x1' + x2'), and fold the "1 - 2r" + w3 weighting:
//   att = sum(w3) - 2 * sum_c w3[c] * rcp(exp2(y_c) + 1)
// Per element: add, min(clamp), v_exp_f32, add, v_rcp_f32, fmac.

#define BATCH 4
#define NN    1024
#define CC    64
#define TI    4      // rows i per block
#define BLK   256
#define NCH   (NN / BLK)   // 4 j-chunks

__device__ __forceinline__ float fast_exp2(float x) {
#if __has_builtin(__builtin_amdgcn_exp2f)
    return __builtin_amdgcn_exp2f(x);
#else
    return exp2f(x);
#endif
}
__device__ __forceinline__ float fast_rcp(float x) {
#if __has_builtin(__builtin_amdgcn_rcpf)
    return __builtin_amdgcn_rcpf(x);
#else
    return 1.0f / x;
#endif
}

// ---------------- Kernel 1: projections, pre-scaled by 2*log2(e) ------------
// x1p[r,d] = K2 * sum_c x[r,c] * W1[d,c];  x2p likewise.  r in [0, B*N).
__global__ __launch_bounds__(256) void proj_kernel(
    const float* __restrict__ x, const float* __restrict__ W1,
    const float* __restrict__ W2, float* __restrict__ x1p,
    float* __restrict__ x2p) {
    const int w    = threadIdx.x >> 6;
    const int lane = threadIdx.x & 63;
    const int r    = blockIdx.x * 4 + w;   // grid = 1024 -> r < 4096
    const float4* __restrict__ xrow  = (const float4*)(x  + (size_t)r    * CC);
    const float4* __restrict__ w1row = (const float4*)(W1 + (size_t)lane * CC);
    const float4* __restrict__ w2row = (const float4*)(W2 + (size_t)lane * CC);
    float a1 = 0.f, a2 = 0.f;
#pragma unroll
    for (int q = 0; q < 16; ++q) {
        float4 xv = xrow[q];
        float4 u  = w1row[q];
        float4 v  = w2row[q];
        a1 = fmaf(xv.x, u.x, a1); a1 = fmaf(xv.y, u.y, a1);
        a1 = fmaf(xv.z, u.z, a1); a1 = fmaf(xv.w, u.w, a1);
        a2 = fmaf(xv.x, v.x, a2); a2 = fmaf(xv.y, v.y, a2);
        a2 = fmaf(xv.z, v.z, a2); a2 = fmaf(xv.w, v.w, a2);
    }
    const float K2 = 2.8853900817779268f;  // 2*log2(e)
    x1p[(size_t)r * CC + lane] = a1 * K2;
    x2p[(size_t)r * CC + lane] = a2 * K2;
}

// ---------------- Kernel 2: fused att + softmax -----------------------------
__global__ __launch_bounds__(BLK, 4) void attn_kernel(
    const float* __restrict__ x1p, const float* __restrict__ x2p,
    const float* __restrict__ w3, float* __restrict__ out) {
    __shared__ float x1t[CC * TI];          // [c][i] transposed: 1 KB
    __shared__ float w3s[CC];
    __shared__ float att_lds[TI * NN];      // 16 KB

    const int tid = threadIdx.x;
    const int bi  = blockIdx.x;             // 1024 blocks
    const int b   = bi >> 8;                // N/TI = 256 blocks per batch
    const int i0  = (bi & 255) * TI;

    // stage x1' tile transposed + w3
    {
        const int ii = tid >> 6, c = tid & 63;
        x1t[c * TI + ii] = x1p[(size_t)((b << 10) + i0 + ii) * CC + c];
        if (tid < CC) w3s[tid] = w3[tid];
    }
    __syncthreads();

    float sumw3 = 0.f;
#pragma unroll
    for (int c = 0; c < CC; ++c) sumw3 += w3s[c];

    const float4* __restrict__ x2r =
        (const float4*)(x2p + ((size_t)b << 10) * CC);
    const float4* x1t4 = (const float4*)x1t;

    for (int ch = 0; ch < NCH; ++ch) {
        const int j = ch * BLK + tid;
        float xr[CC];
        float4* xr4 = (float4*)xr;
#pragma unroll
        for (int q = 0; q < 16; ++q) xr4[q] = x2r[(size_t)j * 16 + q];

        float acc0 = 0.f, acc1 = 0.f, acc2 = 0.f, acc3 = 0.f;
#pragma unroll
        for (int c = 0; c < CC; ++c) {
            const float  xc  = xr[c];
            const float4 xv  = x1t4[c];     // x1'[c][i0..i0+3], LDS broadcast
            const float  w3c = w3s[c];
            float y0 = fminf(xv.x + xc, 126.f);
            float y1 = fminf(xv.y + xc, 126.f);
            float y2 = fminf(xv.z + xc, 126.f);
            float y3 = fminf(xv.w + xc, 126.f);
            float r0 = fast_rcp(fast_exp2(y0) + 1.f);
            float r1 = fast_rcp(fast_exp2(y1) + 1.f);
            float r2 = fast_rcp(fast_exp2(y2) + 1.f);
            float r3 = fast_rcp(fast_exp2(y3) + 1.f);
            acc0 = fmaf(w3c, r0, acc0);
            acc1 = fmaf(w3c, r1, acc1);
            acc2 = fmaf(w3c, r2, acc2);
            acc3 = fmaf(w3c, r3, acc3);
        }
        // att = sum(w3) - 2*acc
        att_lds[0 * NN + j] = fmaf(-2.f, acc0, sumw3);
        att_lds[1 * NN + j] = fmaf(-2.f, acc1, sumw3);
        att_lds[2 * NN + j] = fmaf(-2.f, acc2, sumw3);
        att_lds[3 * NN + j] = fmaf(-2.f, acc3, sumw3);
    }
    __syncthreads();

    // epilogue: wave w softmaxes row i0+w over j
    {
        const int w    = tid >> 6;
        const int lane = tid & 63;
        float v[16];
        float m = -3.4e38f;
#pragma unroll
        for (int k = 0; k < 16; ++k) {
            v[k] = att_lds[w * NN + k * 64 + lane];
            m = fmaxf(m, v[k]);
        }
#pragma unroll
        for (int off = 32; off >= 1; off >>= 1)
            m = fmaxf(m, __shfl_xor(m, off));
        const float L2E = 1.4426950408889634f;
        float s = 0.f;
#pragma unroll
        for (int k = 0; k < 16; ++k) {
            v[k] = fast_exp2((v[k] - m) * L2E);
            s += v[k];
        }
#pragma unroll
        for (int off = 32; off >= 1; off >>= 1)
            s += __shfl_xor(s, off);
        const float rs = fast_rcp(s);
        float* __restrict__ orow = out + (((size_t)(b << 10) + (i0 + w)) << 10);
#pragma unroll
        for (int k = 0; k < 16; ++k) orow[k * 64 + lane] = v[k] * rs;
    }
}

extern "C" void kernel_launch(void* const* d_in, const int* in_sizes, int n_in,
                              void* d_out, int out_size, void* d_ws, size_t ws_size,
                              hipStream_t stream) {
    const float* x  = (const float*)d_in[0];
    const float* W1 = (const float*)d_in[1];
    const float* W2 = (const float*)d_in[2];
    const float* w3 = (const float*)d_in[3];
    float* outp = (float*)d_out;

    float* x1p = (float*)d_ws;                       // 4096*64 fp32 = 1 MB
    float* x2p = x1p + (size_t)BATCH * NN * CC;      // second 1 MB

    proj_kernel<<<dim3(BATCH * NN / 4), dim3(256), 0, stream>>>(x, W1, W2, x1p, x2p);
    attn_kernel<<<dim3(BATCH * NN / TI), dim3(BLK), 0, stream>>>(x1p, x2p, w3, outp);
}